// Round 2
// baseline (449.907 us; speedup 1.0000x reference)
//
#include <hip/hip_runtime.h>
#include <hip/hip_bf16.h>

// CausalLocalAttention: B=4, S=4096, D=1024, H=16, DH=64, W=256 (16 windows)
// Pipeline: cvt_x -> cvt_wT(x4) -> GEMM(Q) -> GEMM(K) -> GEMM(Vt) -> attn -> GEMM(O)

typedef __attribute__((ext_vector_type(4))) float f32x4;
typedef __attribute__((ext_vector_type(8))) short s16x8;
typedef __attribute__((ext_vector_type(4))) short s16x4;

__device__ __forceinline__ short f2bf(float f) {
  unsigned u = __float_as_uint(f);
  u += 0x7fffu + ((u >> 16) & 1u);   // RNE
  return (short)(u >> 16);
}

__device__ __forceinline__ void gload_lds16(const void* g, void* l) {
  __builtin_amdgcn_global_load_lds((const __attribute__((address_space(1))) void*)g,
                                   (__attribute__((address_space(3))) void*)l,
                                   16, 0, 0);
}

__device__ __forceinline__ float rmax16(float v) {
  v = fmaxf(v, __shfl_xor(v, 1, 64));
  v = fmaxf(v, __shfl_xor(v, 2, 64));
  v = fmaxf(v, __shfl_xor(v, 4, 64));
  v = fmaxf(v, __shfl_xor(v, 8, 64));
  return v;
}
__device__ __forceinline__ float rsum16(float v) {
  v += __shfl_xor(v, 1, 64);
  v += __shfl_xor(v, 2, 64);
  v += __shfl_xor(v, 4, 64);
  v += __shfl_xor(v, 8, 64);
  return v;
}

// ---------------- convert x (fp32 -> bf16) ----------------
__global__ void cvt_x(const float4* __restrict__ in, s16x4* __restrict__ out, int n4) {
  for (int i = blockIdx.x * 256 + threadIdx.x; i < n4; i += gridDim.x * 256) {
    float4 v = in[i];
    s16x4 o;
    o[0] = f2bf(v.x); o[1] = f2bf(v.y); o[2] = f2bf(v.z); o[3] = f2bf(v.w);
    out[i] = o;
  }
}

// ------------- convert + transpose weights: W[k][n] fp32 -> Wt[n][k] bf16 -------------
__global__ void cvt_wT(const float* __restrict__ W0, const float* __restrict__ W1,
                       const float* __restrict__ W2, const float* __restrict__ W3,
                       short* __restrict__ out) {
  __shared__ float tile[64][65];
  const float* W = (blockIdx.y == 0) ? W0 : (blockIdx.y == 1) ? W1 : (blockIdx.y == 2) ? W2 : W3;
  short* o = out + (size_t)blockIdx.y * (1024 * 1024);
  const int kt = (blockIdx.x >> 4) << 6, nt = (blockIdx.x & 15) << 6;
  const int tid = threadIdx.x;
#pragma unroll
  for (int i = 0; i < 16; ++i) {
    int lin = i * 256 + tid;
    int r = lin >> 6, c = lin & 63;
    tile[r][c] = W[(size_t)(kt + r) * 1024 + nt + c];
  }
  __syncthreads();
#pragma unroll
  for (int i = 0; i < 16; ++i) {
    int lin = i * 256 + tid;
    int r = lin >> 6, c = lin & 63;
    o[(size_t)(nt + r) * 1024 + kt + c] = f2bf(tile[c][r]);
  }
}

// ---------------- GEMM: C[M,1024] = A[M,1024](bf16) * Wt[1024,1024]^T + bias ----------------
// MODE 0: out bf16 scatter [B,H,S,DH]   (Q, K)
// MODE 1: out bf16 scatter [B,H,DH,S]   (V transposed)
// MODE 2: out fp32 [M,1024] = d_out     (O projection)
template <int MODE>
__global__ __launch_bounds__(256) void gemm_bf16(const short* __restrict__ A,
                                                 const short* __restrict__ Bt,
                                                 const float* __restrict__ bias,
                                                 void* __restrict__ outp) {
  constexpr int Kd = 1024;
  __shared__ short As[128 * 32];
  __shared__ short Bs[128 * 32];
  const int tid = threadIdx.x;
  const int w = tid >> 6, lane = tid & 63;
  const int bm = blockIdx.x >> 3, bn = blockIdx.x & 7;
  const int m0 = bm << 7, n0 = bn << 7;
  const int wr = (w >> 1) << 6, wc = (w & 1) << 6;
  const int srow = lane >> 2, scol = (lane & 3) << 3;  // staging: row-in-16, 8-elem chunk
  const int fr = lane & 15, fk = (lane >> 4) << 3;     // fragment row / k-offset

  f32x4 acc[4][4];
#pragma unroll
  for (int i = 0; i < 4; ++i)
#pragma unroll
    for (int j = 0; j < 4; ++j) acc[i][j] = (f32x4){0.f, 0.f, 0.f, 0.f};

  for (int k0 = 0; k0 < Kd; k0 += 32) {
    __syncthreads();
#pragma unroll
    for (int i = 0; i < 2; ++i) {
      const int rr = ((i * 4 + w) << 4) + srow;
      gload_lds16(A + (size_t)(m0 + rr) * Kd + k0 + scol, As + ((i * 4 + w) << 9));
      gload_lds16(Bt + (size_t)(n0 + rr) * Kd + k0 + scol, Bs + ((i * 4 + w) << 9));
    }
    __syncthreads();
    s16x8 af[4], bf[4];
#pragma unroll
    for (int mi = 0; mi < 4; ++mi) af[mi] = *(const s16x8*)&As[(wr + mi * 16 + fr) * 32 + fk];
#pragma unroll
    for (int ni = 0; ni < 4; ++ni) bf[ni] = *(const s16x8*)&Bs[(wc + ni * 16 + fr) * 32 + fk];
#pragma unroll
    for (int mi = 0; mi < 4; ++mi)
#pragma unroll
      for (int ni = 0; ni < 4; ++ni)
        acc[mi][ni] = __builtin_amdgcn_mfma_f32_16x16x32_bf16(af[mi], bf[ni], acc[mi][ni], 0, 0, 0);
  }

  // epilogue: D layout col=lane&15, row=(lane>>4)*4+reg  (m89-verified)
  const int col0 = n0 + wc + fr;
  const int row0 = m0 + wr + ((lane >> 4) << 2);
#pragma unroll
  for (int mi = 0; mi < 4; ++mi) {
#pragma unroll
    for (int ni = 0; ni < 4; ++ni) {
      const int c = col0 + ni * 16;
      const float bv = bias[c];
#pragma unroll
      for (int jj = 0; jj < 4; ++jj) {
        const int r = row0 + mi * 16 + jj;
        const float v = acc[mi][ni][jj] + bv;
        if (MODE == 2) {
          ((float*)outp)[(size_t)r * 1024 + c] = v;
        } else {
          const int b = r >> 12, s = r & 4095;
          const int h = c >> 6, dh = c & 63;
          size_t addr;
          if (MODE == 0) addr = ((size_t)(b * 16 + h) * 4096 + s) * 64 + dh;
          else           addr = ((size_t)(b * 16 + h) * 64 + dh) * 4096 + s;
          ((short*)outp)[addr] = f2bf(v);
        }
      }
    }
  }
}

// ---------------- windowed causal attention ----------------
// grid = B*H*16 windows; block = 256 (4 waves); wave w owns q-rows [w*64, w*64+64)
__global__ __launch_bounds__(256) void attn_kernel(const short* __restrict__ Qg,
                                                   const short* __restrict__ Kg,
                                                   const short* __restrict__ Vg,
                                                   short* __restrict__ AO) {
  constexpr int S = 4096;
  __shared__ short Pl[4][16][272];  // per-wave P tile, padded (544B rows, 16B aligned)
  const int tid = threadIdx.x;
  const int w = tid >> 6, lane = tid & 63;
  const int fr = lane & 15, g = lane >> 4;
  const int bhn = blockIdx.x;
  const int nb = bhn & 15, bh = bhn >> 4;
  const int b = bh >> 4, h = bh & 15;
  const short* Qb = Qg + ((size_t)bh * S + nb * 256) * 64;
  const short* Kb = Kg + ((size_t)bh * S + nb * 256) * 64;
  const short* Vb = Vg + (size_t)bh * 64 * S + nb * 256;

#pragma unroll
  for (int qi = 0; qi < 4; ++qi) {
    const int qrow = w * 64 + qi * 16;
    const int dmax = w * 4 + qi;  // diagonal 16-col tile index (tiles 0..dmax active)
    const s16x8 aq0 = *(const s16x8*)&Qb[(qrow + fr) * 64 + (g << 3)];
    const s16x8 aq1 = *(const s16x8*)&Qb[(qrow + fr) * 64 + 32 + (g << 3)];
    f32x4 sc[16];
#pragma unroll
    for (int i = 0; i < 16; ++i) sc[i] = (f32x4){0.f, 0.f, 0.f, 0.f};
#pragma unroll
    for (int kt = 0; kt < 16; ++kt) {
      if (kt <= dmax) {
        const s16x8 kf0 = *(const s16x8*)&Kb[(kt * 16 + fr) * 64 + (g << 3)];
        const s16x8 kf1 = *(const s16x8*)&Kb[(kt * 16 + fr) * 64 + 32 + (g << 3)];
        sc[kt] = __builtin_amdgcn_mfma_f32_16x16x32_bf16(aq0, kf0, sc[kt], 0, 0, 0);
        sc[kt] = __builtin_amdgcn_mfma_f32_16x16x32_bf16(aq1, kf1, sc[kt], 0, 0, 0);
      }
    }
    // scale + causal mask (diag tile only) + row max
    float mrow[4] = {-3e38f, -3e38f, -3e38f, -3e38f};
#pragma unroll
    for (int kt = 0; kt < 16; ++kt) {
      if (kt <= dmax) {
#pragma unroll
        for (int jj = 0; jj < 4; ++jj) {
          float v = sc[kt][jj] * 0.125f;
          if (kt == dmax && fr > (g << 2) + jj) v = -3e38f;
          sc[kt][jj] = v;
          mrow[jj] = fmaxf(mrow[jj], v);
        }
      }
    }
#pragma unroll
    for (int jj = 0; jj < 4; ++jj) mrow[jj] = rmax16(mrow[jj]);
    float lsum[4] = {0.f, 0.f, 0.f, 0.f};
#pragma unroll
    for (int kt = 0; kt < 16; ++kt) {
      if (kt <= dmax) {
#pragma unroll
        for (int jj = 0; jj < 4; ++jj) {
          const float p = __expf(sc[kt][jj] - mrow[jj]);
          sc[kt][jj] = p;
          lsum[jj] += p;
        }
      }
    }
#pragma unroll
    for (int jj = 0; jj < 4; ++jj) lsum[jj] = rsum16(lsum[jj]);
    // P -> LDS (D-layout scatter), zero-fill odd trailing tile for 32-wide PV chunks
#pragma unroll
    for (int kt = 0; kt < 16; ++kt) {
      if (kt <= dmax) {
#pragma unroll
        for (int jj = 0; jj < 4; ++jj)
          Pl[w][(g << 2) + jj][kt * 16 + fr] = f2bf(sc[kt][jj]);
      } else if (kt == dmax + 1 && ((dmax + 1) & 1)) {
#pragma unroll
        for (int jj = 0; jj < 4; ++jj) Pl[w][(g << 2) + jj][kt * 16 + fr] = 0;
      }
    }
    asm volatile("s_waitcnt lgkmcnt(0)" ::: "memory");
    // PV: O[64q x 64dh] = P * V, V read as Vt[dh][s] (contiguous 16B per lane)
    f32x4 o[4];
#pragma unroll
    for (int di = 0; di < 4; ++di) o[di] = (f32x4){0.f, 0.f, 0.f, 0.f};
    const int nks2 = (dmax + 2) >> 1;
#pragma unroll
    for (int ks2 = 0; ks2 < 8; ++ks2) {
      if (ks2 < nks2) {
        const s16x8 pa = *(const s16x8*)&Pl[w][fr][ks2 * 32 + (g << 3)];
#pragma unroll
        for (int di = 0; di < 4; ++di) {
          const s16x8 vf = *(const s16x8*)&Vb[(size_t)(di * 16 + fr) * S + ks2 * 32 + (g << 3)];
          o[di] = __builtin_amdgcn_mfma_f32_16x16x32_bf16(pa, vf, o[di], 0, 0, 0);
        }
      }
    }
    float inv[4];
#pragma unroll
    for (int jj = 0; jj < 4; ++jj) inv[jj] = 1.f / lsum[jj];
    const int sg = nb * 256 + qrow + (g << 2);
#pragma unroll
    for (int di = 0; di < 4; ++di) {
#pragma unroll
      for (int jj = 0; jj < 4; ++jj) {
        AO[((size_t)b * S + sg + jj) * 1024 + h * 64 + di * 16 + fr] =
            f2bf(o[di][jj] * inv[jj]);
      }
    }
  }
}

extern "C" void kernel_launch(void* const* d_in, const int* in_sizes, int n_in,
                              void* d_out, int out_size, void* d_ws, size_t ws_size,
                              hipStream_t stream) {
  const float* x  = (const float*)d_in[0];
  const float* Wq = (const float*)d_in[1];
  const float* bq = (const float*)d_in[2];
  const float* Wk = (const float*)d_in[3];
  const float* bk = (const float*)d_in[4];
  const float* Wv = (const float*)d_in[5];
  const float* bv = (const float*)d_in[6];
  const float* Wo = (const float*)d_in[7];
  const float* bo = (const float*)d_in[8];
  float* out = (float*)d_out;

  char* ws = (char*)d_ws;
  short* xb  = (short*)ws;                                   // 32 MB  bf16 x [16384,1024]
  short* Wt  = (short*)(ws + (size_t)33554432);              // 8 MB   Wt q/k/v/o [1024,1024] each
  short* Qb  = (short*)(ws + (size_t)33554432 + 8388608);    // 32 MB  [B,H,S,DH]
  short* Kb  = Qb + (size_t)16777216;                        // 32 MB  [B,H,S,DH]
  short* Vb  = Kb + (size_t)16777216;                        // 32 MB  [B,H,DH,S]
  short* AOb = Vb + (size_t)16777216;                        // 32 MB  [B*S, D]

  cvt_x<<<4096, 256, 0, stream>>>((const float4*)x, (s16x4*)xb, 16777216 / 4);
  cvt_wT<<<dim3(256, 4), 256, 0, stream>>>(Wq, Wk, Wv, Wo, Wt);

  gemm_bf16<0><<<1024, 256, 0, stream>>>(xb, Wt,           bq, Qb);
  gemm_bf16<0><<<1024, 256, 0, stream>>>(xb, Wt + 1048576, bk, Kb);
  gemm_bf16<1><<<1024, 256, 0, stream>>>(xb, Wt + 2097152, bv, Vb);

  attn_kernel<<<1024, 256, 0, stream>>>(Qb, Kb, Vb, AOb);

  gemm_bf16<2><<<1024, 256, 0, stream>>>(AOb, Wt + 3145728, bo, out);
}

// Round 3
// 443.836 us; speedup vs baseline: 1.0137x; 1.0137x over previous
//
#include <hip/hip_runtime.h>
#include <hip/hip_bf16.h>

// CausalLocalAttention: B=4, S=4096, D=1024, H=16, DH=64, W=256 (16 windows)
// Pipeline: cvt_x -> cvt_wT(x4) -> GEMM(QKV fused, dbuf 2-phase) -> attn -> GEMM(O)

typedef __attribute__((ext_vector_type(4))) float f32x4;
typedef __attribute__((ext_vector_type(8))) short s16x8;
typedef __attribute__((ext_vector_type(4))) short s16x4;

__device__ __forceinline__ short f2bf(float f) {
  unsigned u = __float_as_uint(f);
  u += 0x7fffu + ((u >> 16) & 1u);   // RNE
  return (short)(u >> 16);
}

__device__ __forceinline__ void gload_lds16(const void* g, void* l) {
  __builtin_amdgcn_global_load_lds((const __attribute__((address_space(1))) void*)g,
                                   (__attribute__((address_space(3))) void*)l,
                                   16, 0, 0);
}

__device__ __forceinline__ float rmax16(float v) {
  v = fmaxf(v, __shfl_xor(v, 1, 64));
  v = fmaxf(v, __shfl_xor(v, 2, 64));
  v = fmaxf(v, __shfl_xor(v, 4, 64));
  v = fmaxf(v, __shfl_xor(v, 8, 64));
  return v;
}
__device__ __forceinline__ float rsum16(float v) {
  v += __shfl_xor(v, 1, 64);
  v += __shfl_xor(v, 2, 64);
  v += __shfl_xor(v, 4, 64);
  v += __shfl_xor(v, 8, 64);
  return v;
}

// ---------------- convert x (fp32 -> bf16) ----------------
__global__ void cvt_x(const float4* __restrict__ in, s16x4* __restrict__ out, int n4) {
  for (int i = blockIdx.x * 256 + threadIdx.x; i < n4; i += gridDim.x * 256) {
    float4 v = in[i];
    s16x4 o;
    o[0] = f2bf(v.x); o[1] = f2bf(v.y); o[2] = f2bf(v.z); o[3] = f2bf(v.w);
    out[i] = o;
  }
}

// ------------- convert + transpose weights: W[k][n] fp32 -> Wt[n][k] bf16 -------------
__global__ void cvt_wT(const float* __restrict__ W0, const float* __restrict__ W1,
                       const float* __restrict__ W2, const float* __restrict__ W3,
                       short* __restrict__ out) {
  __shared__ float tile[64][65];
  const float* W = (blockIdx.y == 0) ? W0 : (blockIdx.y == 1) ? W1 : (blockIdx.y == 2) ? W2 : W3;
  short* o = out + (size_t)blockIdx.y * (1024 * 1024);
  const int kt = (blockIdx.x >> 4) << 6, nt = (blockIdx.x & 15) << 6;
  const int tid = threadIdx.x;
#pragma unroll
  for (int i = 0; i < 16; ++i) {
    int lin = i * 256 + tid;
    int r = lin >> 6, c = lin & 63;
    tile[r][c] = W[(size_t)(kt + r) * 1024 + nt + c];
  }
  __syncthreads();
#pragma unroll
  for (int i = 0; i < 16; ++i) {
    int lin = i * 256 + tid;
    int r = lin >> 6, c = lin & 63;
    o[(size_t)(nt + r) * 1024 + kt + c] = f2bf(tile[c][r]);
  }
}

// ---------------- GEMM core: C[M, NBN*128] = A[M,1024] * Bt^T + bias ----------------
// Double-buffered 2-phase: STAGE(next) || MFMA(cur), one __syncthreads per K-step.
// Chunked XCD swizzle: 16 bm panels per XCD (A L2-resident), bn-major inner order.
// MODE 0: fused QKV -> bf16 scatter; col block n0: [0,1024)=Q [1024,2048)=K (both
//         [B,H,S,DH]) [2048,3072)=Vt ([B,H,DH,S]).
// MODE 2: fp32 out [M,1024] (O projection).
template <int NBN, int MODE>
__global__ __launch_bounds__(256) void gemm2(const short* __restrict__ A,
                                             const short* __restrict__ BtBase,
                                             const float* __restrict__ b0,
                                             const float* __restrict__ b1,
                                             const float* __restrict__ b2,
                                             short* __restrict__ Qo,
                                             short* __restrict__ Ko,
                                             short* __restrict__ Vo,
                                             float* __restrict__ Oo) {
  constexpr int Kd = 1024;
  __shared__ short As[2][128 * 32];
  __shared__ short Bs[2][128 * 32];
  const int tid = threadIdx.x;
  const int w = tid >> 6, lane = tid & 63;
  // bijective chunked swizzle (grid = NBN*128, %8==0): xcd = blockIdx%8
  const int d = blockIdx.x;
  const int xcd = d & 7, l = d >> 3;
  constexpr int HALF = NBN * 8;
  const int sub = l / HALF, r = l % HALF;
  const int bn = r >> 3, bm = xcd * 16 + sub * 8 + (r & 7);
  const int m0 = bm << 7, n0 = bn << 7;
  const int wr = (w >> 1) << 6, wc = (w & 1) << 6;
  const int srow = lane >> 2, scol = (lane & 3) << 3;
  const int fr = lane & 15, fk = (lane >> 4) << 3;

  const short* Ab  = A + (size_t)m0 * Kd;
  const short* Btb = BtBase + (size_t)(n0 >> 10) * 1048576 + (size_t)(n0 & 1023) * Kd;

  f32x4 acc[4][4];
#pragma unroll
  for (int i = 0; i < 4; ++i)
#pragma unroll
    for (int j = 0; j < 4; ++j) acc[i][j] = (f32x4){0.f, 0.f, 0.f, 0.f};

#define STAGE(buf, kk)                                                        \
  do {                                                                        \
    _Pragma("unroll") for (int i = 0; i < 2; ++i) {                           \
      const int rr = ((i * 4 + w) << 4) + srow;                               \
      gload_lds16(Ab + (size_t)rr * Kd + (kk) + scol, &As[buf][(i * 4 + w) << 9]); \
      gload_lds16(Btb + (size_t)rr * Kd + (kk) + scol, &Bs[buf][(i * 4 + w) << 9]); \
    }                                                                         \
  } while (0)

  STAGE(0, 0);
  __syncthreads();
  int cur = 0;
#pragma unroll 2
  for (int t = 0; t < 32; ++t) {
    if (t < 31) STAGE(cur ^ 1, (t + 1) << 5);
    s16x8 af[4], bf[4];
#pragma unroll
    for (int mi = 0; mi < 4; ++mi) af[mi] = *(const s16x8*)&As[cur][(wr + mi * 16 + fr) * 32 + fk];
#pragma unroll
    for (int ni = 0; ni < 4; ++ni) bf[ni] = *(const s16x8*)&Bs[cur][(wc + ni * 16 + fr) * 32 + fk];
#pragma unroll
    for (int mi = 0; mi < 4; ++mi)
#pragma unroll
      for (int ni = 0; ni < 4; ++ni)
        acc[mi][ni] = __builtin_amdgcn_mfma_f32_16x16x32_bf16(af[mi], bf[ni], acc[mi][ni], 0, 0, 0);
    __syncthreads();   // vmcnt(0)+lgkmcnt(0)+barrier: next tile landed, reads done
    cur ^= 1;
  }
#undef STAGE

  // epilogue: D layout col=lane&15, row=(lane>>4)*4+reg  (m89-verified)
  const int which = n0 >> 10;  // uniform per block (128 | 1024)
  const float* bb = (which == 0) ? b0 : (which == 1) ? b1 : b2;
  const int col0 = n0 + wc + fr;
  const int row0 = m0 + wr + ((lane >> 4) << 2);
#pragma unroll
  for (int mi = 0; mi < 4; ++mi) {
#pragma unroll
    for (int ni = 0; ni < 4; ++ni) {
      const int c = col0 + ni * 16;
      const float bv = bb[c & 1023];
#pragma unroll
      for (int jj = 0; jj < 4; ++jj) {
        const int rrow = row0 + mi * 16 + jj;
        const float v = acc[mi][ni][jj] + bv;
        if (MODE == 2) {
          Oo[(size_t)rrow * 1024 + c] = v;
        } else {
          const int b = rrow >> 12, s = rrow & 4095;
          const int cl = c & 1023;
          const int h = cl >> 6, dh = cl & 63;
          short* ob = (which == 0) ? Qo : (which == 1) ? Ko : Vo;
          size_t addr;
          if (which < 2) addr = ((size_t)(b * 16 + h) * 4096 + s) * 64 + dh;
          else           addr = ((size_t)(b * 16 + h) * 64 + dh) * 4096 + s;
          ob[addr] = f2bf(v);
        }
      }
    }
  }
}

// ---------------- windowed causal attention ----------------
// grid = B*H*16 windows; block = 256 (4 waves); wave w owns q-rows [w*64, w*64+64)
__global__ __launch_bounds__(256) void attn_kernel(const short* __restrict__ Qg,
                                                   const short* __restrict__ Kg,
                                                   const short* __restrict__ Vg,
                                                   short* __restrict__ AO) {
  constexpr int S = 4096;
  __shared__ short Pl[4][16][272];  // per-wave P tile, padded (544B rows, 16B aligned)
  const int tid = threadIdx.x;
  const int w = tid >> 6, lane = tid & 63;
  const int fr = lane & 15, g = lane >> 4;
  const int bhn = blockIdx.x;
  const int nb = bhn & 15, bh = bhn >> 4;
  const int b = bh >> 4, h = bh & 15;
  const short* Qb = Qg + ((size_t)bh * S + nb * 256) * 64;
  const short* Kb = Kg + ((size_t)bh * S + nb * 256) * 64;
  const short* Vb = Vg + (size_t)bh * 64 * S + nb * 256;

#pragma unroll
  for (int qi = 0; qi < 4; ++qi) {
    const int qrow = w * 64 + qi * 16;
    const int dmax = w * 4 + qi;  // diagonal 16-col tile index (tiles 0..dmax active)
    const s16x8 aq0 = *(const s16x8*)&Qb[(qrow + fr) * 64 + (g << 3)];
    const s16x8 aq1 = *(const s16x8*)&Qb[(qrow + fr) * 64 + 32 + (g << 3)];
    f32x4 sc[16];
#pragma unroll
    for (int i = 0; i < 16; ++i) sc[i] = (f32x4){0.f, 0.f, 0.f, 0.f};
#pragma unroll
    for (int kt = 0; kt < 16; ++kt) {
      if (kt <= dmax) {
        const s16x8 kf0 = *(const s16x8*)&Kb[(kt * 16 + fr) * 64 + (g << 3)];
        const s16x8 kf1 = *(const s16x8*)&Kb[(kt * 16 + fr) * 64 + 32 + (g << 3)];
        sc[kt] = __builtin_amdgcn_mfma_f32_16x16x32_bf16(aq0, kf0, sc[kt], 0, 0, 0);
        sc[kt] = __builtin_amdgcn_mfma_f32_16x16x32_bf16(aq1, kf1, sc[kt], 0, 0, 0);
      }
    }
    // scale + causal mask (diag tile only) + row max
    float mrow[4] = {-3e38f, -3e38f, -3e38f, -3e38f};
#pragma unroll
    for (int kt = 0; kt < 16; ++kt) {
      if (kt <= dmax) {
#pragma unroll
        for (int jj = 0; jj < 4; ++jj) {
          float v = sc[kt][jj] * 0.125f;
          if (kt == dmax && fr > (g << 2) + jj) v = -3e38f;
          sc[kt][jj] = v;
          mrow[jj] = fmaxf(mrow[jj], v);
        }
      }
    }
#pragma unroll
    for (int jj = 0; jj < 4; ++jj) mrow[jj] = rmax16(mrow[jj]);
    float lsum[4] = {0.f, 0.f, 0.f, 0.f};
#pragma unroll
    for (int kt = 0; kt < 16; ++kt) {
      if (kt <= dmax) {
#pragma unroll
        for (int jj = 0; jj < 4; ++jj) {
          const float p = __expf(sc[kt][jj] - mrow[jj]);
          sc[kt][jj] = p;
          lsum[jj] += p;
        }
      }
    }
#pragma unroll
    for (int jj = 0; jj < 4; ++jj) lsum[jj] = rsum16(lsum[jj]);
    // P -> LDS (D-layout scatter), zero-fill odd trailing tile for 32-wide PV chunks
#pragma unroll
    for (int kt = 0; kt < 16; ++kt) {
      if (kt <= dmax) {
#pragma unroll
        for (int jj = 0; jj < 4; ++jj)
          Pl[w][(g << 2) + jj][kt * 16 + fr] = f2bf(sc[kt][jj]);
      } else if (kt == dmax + 1 && ((dmax + 1) & 1)) {
#pragma unroll
        for (int jj = 0; jj < 4; ++jj) Pl[w][(g << 2) + jj][kt * 16 + fr] = 0;
      }
    }
    asm volatile("s_waitcnt lgkmcnt(0)" ::: "memory");
    // PV: O[64q x 64dh] = P * V, V read as Vt[dh][s] (contiguous 16B per lane)
    f32x4 o[4];
#pragma unroll
    for (int di = 0; di < 4; ++di) o[di] = (f32x4){0.f, 0.f, 0.f, 0.f};
    const int nks2 = (dmax + 2) >> 1;
#pragma unroll
    for (int ks2 = 0; ks2 < 8; ++ks2) {
      if (ks2 < nks2) {
        const s16x8 pa = *(const s16x8*)&Pl[w][fr][ks2 * 32 + (g << 3)];
#pragma unroll
        for (int di = 0; di < 4; ++di) {
          const s16x8 vf = *(const s16x8*)&Vb[(size_t)(di * 16 + fr) * S + ks2 * 32 + (g << 3)];
          o[di] = __builtin_amdgcn_mfma_f32_16x16x32_bf16(pa, vf, o[di], 0, 0, 0);
        }
      }
    }
    float inv[4];
#pragma unroll
    for (int jj = 0; jj < 4; ++jj) inv[jj] = 1.f / lsum[jj];
    const int sg = nb * 256 + qrow + (g << 2);
#pragma unroll
    for (int di = 0; di < 4; ++di) {
#pragma unroll
      for (int jj = 0; jj < 4; ++jj) {
        AO[((size_t)b * S + sg + jj) * 1024 + h * 64 + di * 16 + fr] =
            f2bf(o[di][jj] * inv[jj]);
      }
    }
  }
}

extern "C" void kernel_launch(void* const* d_in, const int* in_sizes, int n_in,
                              void* d_out, int out_size, void* d_ws, size_t ws_size,
                              hipStream_t stream) {
  const float* x  = (const float*)d_in[0];
  const float* Wq = (const float*)d_in[1];
  const float* bq = (const float*)d_in[2];
  const float* Wk = (const float*)d_in[3];
  const float* bk = (const float*)d_in[4];
  const float* Wv = (const float*)d_in[5];
  const float* bv = (const float*)d_in[6];
  const float* Wo = (const float*)d_in[7];
  const float* bo = (const float*)d_in[8];
  float* out = (float*)d_out;

  char* ws = (char*)d_ws;
  short* xb  = (short*)ws;                                   // 32 MB  bf16 x [16384,1024]
  short* Wt  = (short*)(ws + (size_t)33554432);              // 8 MB   Wt q/k/v/o [1024,1024] each
  short* Qb  = (short*)(ws + (size_t)33554432 + 8388608);    // 32 MB  [B,H,S,DH]
  short* Kb  = Qb + (size_t)16777216;                        // 32 MB  [B,H,S,DH]
  short* Vb  = Kb + (size_t)16777216;                        // 32 MB  [B,H,DH,S]
  short* AOb = Vb + (size_t)16777216;                        // 32 MB  [B*S, D]

  cvt_x<<<4096, 256, 0, stream>>>((const float4*)x, (s16x4*)xb, 16777216 / 4);
  cvt_wT<<<dim3(256, 4), 256, 0, stream>>>(Wq, Wk, Wv, Wo, Wt);

  // fused QKV: grid = 128 bm * 24 bn = 3072
  gemm2<24, 0><<<3072, 256, 0, stream>>>(xb, Wt, bq, bk, bv, Qb, Kb, Vb, nullptr);

  attn_kernel<<<1024, 256, 0, stream>>>(Qb, Kb, Vb, AOb);

  // O projection: grid = 128 bm * 8 bn = 1024
  gemm2<8, 2><<<1024, 256, 0, stream>>>(AOb, Wt + 3145728, bo, bo, bo,
                                        nullptr, nullptr, nullptr, out);
}